// Round 6
// baseline (391.173 us; speedup 1.0000x reference)
//
#include <hip/hip_runtime.h>
#include <hip/hip_bf16.h>

// Problem constants
#define BB 32
#define QQ 300
#define DD 256
#define HH 8
#define DHH 32
#define LL 4
#define PP 4
#define SS 8500
#define NTILES 2125   // 272000 / 128
#define VGRID 256     // persistent blocks (1/CU, LDS-capped)

typedef __attribute__((ext_vector_type(8))) short bf16x8;
typedef __attribute__((ext_vector_type(4))) float f32x4;

__device__ inline unsigned short f2bf(float f) {
  unsigned int u = __builtin_bit_cast(unsigned int, f);
  unsigned int r = (u + 0x7FFFu + ((u >> 16) & 1u)) >> 16;
  return (unsigned short)r;
}

// ---------------------------------------------------------------------------
// Convert W_val (256x256 f32, [k][n]) -> bf16 [n][k] with T2 XOR swizzle
// (k ^= (n&7)<<3) so GEMM ds_read_b128 fragment reads are bank-conflict-free.
// ---------------------------------------------------------------------------
__global__ __launch_bounds__(256) void wcvt_kernel(const float* __restrict__ W,
                                                   unsigned short* __restrict__ wbfS) {
  int t = blockIdx.x * 256 + threadIdx.x;   // 0..65535
  int k = t >> 8, n = t & 255;              // coalesced read of W[k][*]
  wbfS[n * 256 + (k ^ ((n & 7) << 3))] = f2bf(W[(size_t)k * 256 + n]);
}

// ---------------------------------------------------------------------------
// Value GEMM: C[M x 256] = bf16(A[M x 256] f32) @ bf16(W) + bias.
// Whole B resident in LDS (128 KiB, swizzled). A streams global->reg->MFMA,
// one K-step prefetch ahead. NO barriers in the K-loop. Persistent blocks
// grid-stride over M-tiles (BM=128). 8 waves = 4m x 2n, wave tile 32x128.
// ---------------------------------------------------------------------------
__global__ __launch_bounds__(512, 2) void gemm_val_mfma(
    const float* __restrict__ A, const unsigned short* __restrict__ WbfS,
    const float* __restrict__ bias, __hip_bfloat16* __restrict__ C) {
  __shared__ __align__(16) unsigned short Blds[65536];   // 128 KiB

  const int t = threadIdx.x;
  const int lane = t & 63;
  const int wid = t >> 6;
  const int wm = wid >> 1;        // 0..3  row block of 32
  const int wn = wid & 1;         // 0..1  col block of 128
  const int lm = lane & 15, lg = lane >> 4, l7 = lane & 7;

  // Stage all of B (pre-swizzled in memory -> linear copy) into LDS, once.
  {
    const uint4* src = reinterpret_cast<const uint4*>(WbfS);
    uint4* dst = reinterpret_cast<uint4*>(Blds);
#pragma unroll
    for (int i = 0; i < 16; ++i) dst[i * 512 + t] = src[i * 512 + t];
  }
  __syncthreads();   // the ONLY barrier

  // Per-lane B-fragment addressing (bytes). Element (n, k):
  // byte = n*512 + 2*(k ^ ((n&7)<<3));  n&7 == lane&7 (lane-const).
  const int msk = l7 << 4;
  const int eks0 = (lg * 16) ^ msk;          // ks=0
  const int eks1 = (64 + lg * 16) ^ msk;     // ks=1
  const char* bldsc = reinterpret_cast<const char*>(Blds);
  const int bB = (wn * 128 + lm) * 512;

  float bv[8];
#pragma unroll
  for (int nf = 0; nf < 8; ++nf) bv[nf] = bias[wn * 128 + nf * 16 + lm];

  f32x4 acc[2][8];
#pragma unroll
  for (int mf = 0; mf < 2; ++mf)
#pragma unroll
    for (int nf = 0; nf < 8; ++nf) acc[mf][nf] = {0.f, 0.f, 0.f, 0.f};

  float4 ast[2][2][2];   // staged A: [mf][ks][half], always 1 K-step ahead

  auto load_stage = [&](int rowbase, int k0) {
#pragma unroll
    for (int mf = 0; mf < 2; ++mf)
#pragma unroll
      for (int ks = 0; ks < 2; ++ks) {
        const float* p = A + (size_t)(rowbase + mf * 16 + lm) * 256 + k0 + ks * 32 + lg * 8;
        ast[mf][ks][0] = *reinterpret_cast<const float4*>(p);
        ast[mf][ks][1] = *reinterpret_cast<const float4*>(p + 4);
      }
  };

  auto cvt8 = [&](const float4& a, const float4& b) -> bf16x8 {
    bf16x8 r;
    r[0] = (short)f2bf(a.x); r[1] = (short)f2bf(a.y);
    r[2] = (short)f2bf(a.z); r[3] = (short)f2bf(a.w);
    r[4] = (short)f2bf(b.x); r[5] = (short)f2bf(b.y);
    r[6] = (short)f2bf(b.z); r[7] = (short)f2bf(b.w);
    return r;
  };

  auto kstep = [&](int k0, int pf_rowbase, int pf_k0, bool do_pf) {
    bf16x8 af[2][2];
#pragma unroll
    for (int mf = 0; mf < 2; ++mf)
#pragma unroll
      for (int ks = 0; ks < 2; ++ks)
        af[mf][ks] = cvt8(ast[mf][ks][0], ast[mf][ks][1]);
    if (do_pf) load_stage(pf_rowbase, pf_k0);   // next step's loads in flight
#pragma unroll
    for (int ks = 0; ks < 2; ++ks) {
      const int ek = ks ? eks1 : eks0;
      bf16x8 bf[8];
#pragma unroll
      for (int nf = 0; nf < 8; ++nf)
        bf[nf] = *reinterpret_cast<const bf16x8*>(bldsc + bB + nf * 8192 + k0 * 2 + ek);
#pragma unroll
      for (int mf = 0; mf < 2; ++mf)
#pragma unroll
        for (int nf = 0; nf < 8; ++nf)
          acc[mf][nf] = __builtin_amdgcn_mfma_f32_16x16x32_bf16(af[mf][ks], bf[nf], acc[mf][nf], 0, 0, 0);
    }
  };

  int tile = blockIdx.x;
  load_stage(tile * 128 + wm * 32, 0);
  for (; tile < NTILES; tile += VGRID) {
    const int rb = tile * 128 + wm * 32;
    const int ntile = tile + VGRID;
    const bool pf = ntile < NTILES;
    kstep(0, rb, 64, true);
    kstep(64, rb, 128, true);
    kstep(128, rb, 192, true);
    kstep(192, pf ? (ntile * 128 + wm * 32) : rb, 0, pf);

    // Epilogue: C/D layout col=lane&15, row=(lane>>4)*4+j
#pragma unroll
    for (int mf = 0; mf < 2; ++mf) {
      const int rbase = rb + mf * 16 + lg * 4;
#pragma unroll
      for (int nf = 0; nf < 8; ++nf) {
        const int col = wn * 128 + nf * 16 + lm;
#pragma unroll
        for (int j = 0; j < 4; ++j)
          C[(size_t)(rbase + j) * 256 + col] = __float2bfloat16(acc[mf][nf][j] + bv[nf]);
        acc[mf][nf] = {0.f, 0.f, 0.f, 0.f};
      }
    }
  }
}

// ---------------------------------------------------------------------------
// fp32 tiled GEMM for the small projections.
// ---------------------------------------------------------------------------
__device__ inline void store_val(float* p, float v) { *p = v; }
__device__ inline void store_val(__hip_bfloat16* p, float v) { *p = __float2bfloat16(v); }

template <int BN, typename OUT_T>
__global__ __launch_bounds__(256) void gemm_rowtile(
    const float* __restrict__ A, const float* __restrict__ W,
    const float* __restrict__ bias, OUT_T* __restrict__ C) {
  constexpr int K = 256, BK = 32, BM = 64;
  constexpr int NJ = BN / 32;
  __shared__ float As[BM][BK + 1];
  __shared__ float Bs[BK][BN];

  const int t = threadIdx.x;
  const int row0 = blockIdx.x * BM;
  const int tm = t >> 5;
  const int tn = t & 31;

  float acc[8][NJ];
#pragma unroll
  for (int i = 0; i < 8; ++i)
#pragma unroll
    for (int j = 0; j < NJ; ++j) acc[i][j] = 0.f;

  for (int k0 = 0; k0 < K; k0 += BK) {
#pragma unroll
    for (int i = 0; i < (BM * BK) / 256; ++i) {
      int idx = t + i * 256;
      int r = idx / BK, kk = idx % BK;
      As[r][kk] = A[(size_t)(row0 + r) * K + (k0 + kk)];
    }
#pragma unroll
    for (int i = 0; i < (BK * BN) / 256; ++i) {
      int idx = t + i * 256;
      int kk = idx / BN, n = idx % BN;
      Bs[kk][n] = W[(size_t)(k0 + kk) * BN + n];
    }
    __syncthreads();

#pragma unroll
    for (int kk = 0; kk < BK; ++kk) {
      float a[8], bb[NJ];
#pragma unroll
      for (int i = 0; i < 8; ++i) a[i] = As[tm * 8 + i][kk];
#pragma unroll
      for (int j = 0; j < NJ; ++j) bb[j] = Bs[kk][tn + j * 32];
#pragma unroll
      for (int i = 0; i < 8; ++i)
#pragma unroll
        for (int j = 0; j < NJ; ++j) acc[i][j] += a[i] * bb[j];
    }
    __syncthreads();
  }

#pragma unroll
  for (int i = 0; i < 8; ++i) {
    const size_t row = (size_t)row0 + tm * 8 + i;
#pragma unroll
    for (int j = 0; j < NJ; ++j) {
      const int col = tn + j * 32;
      store_val(&C[row * BN + col], acc[i][j] + bias[col]);
    }
  }
}

// ---------------------------------------------------------------------------
// Bilinear sampling + fused softmax + weighted sum.
// 32 threads per query: h = 0..7, c4 = 0..3 (8 channels each, uint4 taps).
// ---------------------------------------------------------------------------
#define QPB 8

__global__ __launch_bounds__(256) void sample_kernel(
    const __hip_bfloat16* __restrict__ value, const float* __restrict__ off,
    const float* __restrict__ logits, const float* __restrict__ refpts,
    float* __restrict__ sampled) {
  __shared__ float s_off[QPB][256];
  __shared__ float s_lg[QPB][128];
  __shared__ float s_ref[QPB][4];

  const int nb = gridDim.x;
  const int bswz = (blockIdx.x % 8) * (nb / 8) + blockIdx.x / 8;
  const int bq0 = bswz * QPB;
  const int t = threadIdx.x;

  for (int i = t; i < QPB * 256; i += 256) s_off[i >> 8][i & 255] = off[(size_t)bq0 * 256 + i];
  for (int i = t; i < QPB * 128; i += 256) s_lg[i >> 7][i & 127] = logits[(size_t)bq0 * 128 + i];
  if (t < QPB * 4) s_ref[t >> 2][t & 3] = refpts[(size_t)bq0 * 4 + t];
  __syncthreads();

  const int qi = t >> 5;
  const int sub = t & 31;
  const int h = sub >> 2;
  const int c4 = sub & 3;
  const int bq = bq0 + qi;
  const int b = bq / QQ;

  float w[16];
  {
    const float* lg = &s_lg[qi][h * 16];
    float m = lg[0];
#pragma unroll
    for (int j = 1; j < 16; ++j) m = fmaxf(m, lg[j]);
    float s = 0.f;
#pragma unroll
    for (int j = 0; j < 16; ++j) { w[j] = __expf(lg[j] - m); s += w[j]; }
    float inv = 1.f / s;
#pragma unroll
    for (int j = 0; j < 16; ++j) w[j] *= inv;
  }

  const float rx = s_ref[qi][0], ry = s_ref[qi][1];
  const float rw = s_ref[qi][2], rh = s_ref[qi][3];
  const unsigned short* vb =
      (const unsigned short*)value + (size_t)b * SS * DD + h * DHH + c4 * 8;

  float acc[8];
#pragma unroll
  for (int j = 0; j < 8; ++j) acc[j] = 0.f;

  const int dims[4] = {80, 40, 20, 10};
  const int sts[4] = {0, 6400, 8000, 8400};

#pragma unroll
  for (int l = 0; l < LL; ++l) {
    const int dim = dims[l];
    const int st = sts[l];
    const float fdim = (float)dim;
#pragma unroll
    for (int p = 0; p < PP; ++p) {
      const int tapi = l * 4 + p;
      const int oi = (h * 16 + tapi) * 2;
      const float locx = rx + s_off[qi][oi] * rw * 0.125f;
      const float locy = ry + s_off[qi][oi + 1] * rh * 0.125f;
      const float x = locx * fdim - 0.5f;
      const float y = locy * fdim - 0.5f;
      const float x0f = floorf(x), y0f = floorf(y);
      const float fx = x - x0f, fy = y - y0f;
      const int x0 = (int)x0f, y0 = (int)y0f;
      const float wt = w[tapi];
      const float bw[4] = {(1.f - fx) * (1.f - fy), fx * (1.f - fy),
                           (1.f - fx) * fy, fx * fy};
      const int cx[4] = {x0, x0 + 1, x0, x0 + 1};
      const int cy[4] = {y0, y0, y0 + 1, y0 + 1};
#pragma unroll
      for (int c = 0; c < 4; ++c) {
        const int xi = cx[c], yi = cy[c];
        const bool valid = (xi >= 0) & (xi < dim) & (yi >= 0) & (yi < dim);
        const int xc = min(max(xi, 0), dim - 1);
        const int yc = min(max(yi, 0), dim - 1);
        const uint4 v = *reinterpret_cast<const uint4*>(
            vb + (size_t)(st + yc * dim + xc) * DD);
        const float wv = valid ? bw[c] * wt : 0.f;
        const unsigned u[4] = {v.x, v.y, v.z, v.w};
#pragma unroll
        for (int k = 0; k < 4; ++k) {
          const float lo = __builtin_bit_cast(float, u[k] << 16);
          const float hi = __builtin_bit_cast(float, u[k] & 0xFFFF0000u);
          acc[2 * k] += lo * wv;
          acc[2 * k + 1] += hi * wv;
        }
      }
    }
  }

  float* outp = &sampled[(size_t)bq * 256 + h * DHH + c4 * 8];
  *reinterpret_cast<float4*>(outp) = make_float4(acc[0], acc[1], acc[2], acc[3]);
  *reinterpret_cast<float4*>(outp + 4) = make_float4(acc[4], acc[5], acc[6], acc[7]);
}

// ---------------------------------------------------------------------------
// Launch
// ---------------------------------------------------------------------------
extern "C" void kernel_launch(void* const* d_in, const int* in_sizes, int n_in,
                              void* d_out, int out_size, void* d_ws, size_t ws_size,
                              hipStream_t stream) {
  const float* hidden = (const float*)d_in[0];
  const float* ehs    = (const float*)d_in[1];
  const float* refpts = (const float*)d_in[2];
  const float* W_val  = (const float*)d_in[3];
  const float* b_val  = (const float*)d_in[4];
  const float* W_off  = (const float*)d_in[5];
  const float* b_off  = (const float*)d_in[6];
  const float* W_attn = (const float*)d_in[7];
  const float* b_attn = (const float*)d_in[8];
  const float* W_out  = (const float*)d_in[9];
  const float* b_out  = (const float*)d_in[10];
  float* out = (float*)d_out;

  // Workspace layout
  char* ws = (char*)d_ws;
  __hip_bfloat16* value = (__hip_bfloat16*)ws;                 // 139,264,000 B
  float* offb = (float*)(ws + 139264000);                      // 9,830,400 B
  float* awb  = (float*)(ws + 139264000 + 9830400);            // 4,915,200 B
  float* samp = (float*)(ws + 139264000 + 9830400 + 4915200);  // 9,830,400 B
  unsigned short* wbfS = (unsigned short*)(ws + 139264000 + 9830400 + 4915200 + 9830400);

  const int M_q = BB * QQ;   // 9600

  // 0. W_val -> bf16 [n][k], XOR-swizzled
  wcvt_kernel<<<256, 256, 0, stream>>>(W_val, wbfS);
  // 1. value = ehs @ W_val + b_val  (bf16, MFMA, B-in-LDS streaming design)
  gemm_val_mfma<<<VGRID, 512, 0, stream>>>(ehs, wbfS, b_val, value);
  // 2. off = hidden @ W_off + b_off  (fp32 — feeds sample positions)
  gemm_rowtile<256, float><<<M_q / 64, 256, 0, stream>>>(hidden, W_off, b_off, offb);
  // 3. aw logits = hidden @ W_attn + b_attn (softmax fused into sampling)
  gemm_rowtile<128, float><<<M_q / 64, 256, 0, stream>>>(hidden, W_attn, b_attn, awb);
  // 4. bilinear sampling + fused softmax + weighted sum
  sample_kernel<<<M_q / QPB, 256, 0, stream>>>(value, offb, awb, refpts, samp);
  // 5. out = samp @ W_out + b_out
  gemm_rowtile<256, float><<<M_q / 64, 256, 0, stream>>>(samp, W_out, b_out, out);
}

// Round 7
// 271.769 us; speedup vs baseline: 1.4394x; 1.4394x over previous
//
#include <hip/hip_runtime.h>
#include <hip/hip_bf16.h>

// Problem constants
#define BB 32
#define QQ 300
#define DD 256
#define HH 8
#define DHH 32
#define LL 4
#define PP 4
#define SS 8500

typedef __attribute__((ext_vector_type(8))) short bf16x8;
typedef __attribute__((ext_vector_type(4))) float f32x4;

__device__ inline unsigned short f2bf(float f) {
  unsigned int u = __builtin_bit_cast(unsigned int, f);
  unsigned int r = (u + 0x7FFFu + ((u >> 16) & 1u)) >> 16;
  return (unsigned short)r;
}

// ---------------------------------------------------------------------------
// Convert W_val (256x256 f32, [k][n]) -> bf16 [n][k] with T2 XOR swizzle
// (k ^= (n&7)<<3; mask < 64 so each 64-aligned k-window is self-contained).
// ---------------------------------------------------------------------------
__global__ __launch_bounds__(256) void wcvt_kernel(const float* __restrict__ W,
                                                   unsigned short* __restrict__ wbfS) {
  int t = blockIdx.x * 256 + threadIdx.x;   // 0..65535
  int k = t >> 8, n = t & 255;              // coalesced read of W[k][*]
  wbfS[n * 256 + (k ^ ((n & 7) << 3))] = f2bf(W[(size_t)k * 256 + n]);
}

// ---------------------------------------------------------------------------
// Value GEMM: C[M x 256] = bf16(A[M x 256] f32) @ bf16(W) + bias.
// 256 threads = 4 waves; BM=64 (wave owns 16 rows x all 256 cols -> A read
// ONCE, no duplication). B tile staged async via global_load_lds (bf16,
// pre-swizzled source -> linear LDS lands swizzled). A reg-staged fp32->bf16.
// R3 barrier structure (no hand pipeline); 3 blocks/CU hide the drain.
// ---------------------------------------------------------------------------
__global__ __launch_bounds__(256, 3) void gemm_val_mfma(
    const float* __restrict__ A, const unsigned short* __restrict__ WbfS,
    const float* __restrict__ bias, __hip_bfloat16* __restrict__ C) {
  __shared__ unsigned short Alds[64][72];                 // 9.2 KB, pad-8
  __shared__ __align__(16) unsigned short Blds[256 * 64]; // 32 KB, [n][kk] swizzled

  const int t = threadIdx.x;
  const int lane = t & 63;
  const int w = t >> 6;            // wave 0..3 -> rows w*16..w*16+15
  const int lm = lane & 15, lg = lane >> 4;
  const int row0 = blockIdx.x * 64;

  f32x4 acc[16];
#pragma unroll
  for (int nf = 0; nf < 16; ++nf) acc[nf] = {0.f, 0.f, 0.f, 0.f};

  for (int k0 = 0; k0 < 256; k0 += 64) {
    // --- B: 8 async global_load_lds (16 B) per wave, zero VGPR ---
    // LDS chunk c = w*8+i covers rows n = c*8 .. c*8+7 (128 B each).
#pragma unroll
    for (int i = 0; i < 8; ++i) {
      const unsigned short* gp = WbfS +
          (size_t)(w * 64 + i * 8 + (lane >> 3)) * 256 + k0 + (lane & 7) * 8;
      unsigned char* lp = reinterpret_cast<unsigned char*>(Blds) + (w * 8 + i) * 1024;
      __builtin_amdgcn_global_load_lds(
          (const __attribute__((address_space(1))) void*)gp,
          (__attribute__((address_space(3))) void*)lp, 16, 0, 0);
    }
    // --- A: 64 rows x 64 f32 -> bf16 into Alds ---
#pragma unroll
    for (int i = 0; i < 4; ++i) {
      int u = i * 256 + t;
      int r = u >> 4, c4 = (u & 15) * 4;
      float4 v = *reinterpret_cast<const float4*>(A + (size_t)(row0 + r) * 256 + k0 + c4);
      ushort4 h;
      h.x = f2bf(v.x); h.y = f2bf(v.y); h.z = f2bf(v.z); h.w = f2bf(v.w);
      *reinterpret_cast<ushort4*>(&Alds[r][c4]) = h;
    }
    __syncthreads();

    // --- compute: 2 ks x 16 nf MFMA per wave ---
#pragma unroll
    for (int ks = 0; ks < 2; ++ks) {
      const bf16x8 af = *reinterpret_cast<const bf16x8*>(&Alds[w * 16 + lm][ks * 32 + lg * 8]);
      const int kk = (ks * 32 + lg * 8) ^ ((lm & 7) << 3);   // un-swizzle
#pragma unroll
      for (int nf = 0; nf < 16; ++nf) {
        const bf16x8 bfr = *reinterpret_cast<const bf16x8*>(&Blds[(nf * 16 + lm) * 64 + kk]);
        acc[nf] = __builtin_amdgcn_mfma_f32_16x16x32_bf16(af, bfr, acc[nf], 0, 0, 0);
      }
    }
    __syncthreads();
  }

  // Epilogue: C/D layout col=lane&15, row=(lane>>4)*4+j
  const int rb = row0 + w * 16 + lg * 4;
#pragma unroll
  for (int nf = 0; nf < 16; ++nf) {
    const int col = nf * 16 + lm;
    const float bv = bias[col];
#pragma unroll
    for (int j = 0; j < 4; ++j)
      C[(size_t)(rb + j) * 256 + col] = __float2bfloat16(acc[nf][j] + bv);
  }
}

// ---------------------------------------------------------------------------
// fp32 tiled GEMM for the small projections. BM=32 -> 300 blocks (tail fix).
// ---------------------------------------------------------------------------
__device__ inline void store_val(float* p, float v) { *p = v; }
__device__ inline void store_val(__hip_bfloat16* p, float v) { *p = __float2bfloat16(v); }

template <int BN, typename OUT_T>
__global__ __launch_bounds__(256) void gemm_rowtile(
    const float* __restrict__ A, const float* __restrict__ W,
    const float* __restrict__ bias, OUT_T* __restrict__ C) {
  constexpr int K = 256, BK = 32, BM = 32;
  constexpr int NJ = BN / 32;
  __shared__ float As[BM][BK + 1];
  __shared__ float Bs[BK][BN];

  const int t = threadIdx.x;
  const int row0 = blockIdx.x * BM;
  const int tm = t >> 5;   // 0..7, 4 rows each
  const int tn = t & 31;

  float acc[4][NJ];
#pragma unroll
  for (int i = 0; i < 4; ++i)
#pragma unroll
    for (int j = 0; j < NJ; ++j) acc[i][j] = 0.f;

  for (int k0 = 0; k0 < K; k0 += BK) {
#pragma unroll
    for (int i = 0; i < (BM * BK) / 256; ++i) {
      int idx = t + i * 256;
      int r = idx / BK, kk = idx % BK;
      As[r][kk] = A[(size_t)(row0 + r) * K + (k0 + kk)];
    }
#pragma unroll
    for (int i = 0; i < (BK * BN) / 256; ++i) {
      int idx = t + i * 256;
      int kk = idx / BN, n = idx % BN;
      Bs[kk][n] = W[(size_t)(k0 + kk) * BN + n];
    }
    __syncthreads();

#pragma unroll
    for (int kk = 0; kk < BK; ++kk) {
      float a[4], bb[NJ];
#pragma unroll
      for (int i = 0; i < 4; ++i) a[i] = As[tm * 4 + i][kk];
#pragma unroll
      for (int j = 0; j < NJ; ++j) bb[j] = Bs[kk][tn + j * 32];
#pragma unroll
      for (int i = 0; i < 4; ++i)
#pragma unroll
        for (int j = 0; j < NJ; ++j) acc[i][j] += a[i] * bb[j];
    }
    __syncthreads();
  }

#pragma unroll
  for (int i = 0; i < 4; ++i) {
    const size_t row = (size_t)row0 + tm * 4 + i;
#pragma unroll
    for (int j = 0; j < NJ; ++j) {
      const int col = tn + j * 32;
      store_val(&C[row * BN + col], acc[i][j] + bias[col]);
    }
  }
}

// ---------------------------------------------------------------------------
// Bilinear sampling + fused softmax + weighted sum.
// 32 threads per query: h = 0..7, c4 = 0..3 (8 channels each, uint4 taps).
// ---------------------------------------------------------------------------
#define QPB 8

__global__ __launch_bounds__(256) void sample_kernel(
    const __hip_bfloat16* __restrict__ value, const float* __restrict__ off,
    const float* __restrict__ logits, const float* __restrict__ refpts,
    float* __restrict__ sampled) {
  __shared__ float s_off[QPB][256];
  __shared__ float s_lg[QPB][128];
  __shared__ float s_ref[QPB][4];

  const int nb = gridDim.x;
  const int bswz = (blockIdx.x % 8) * (nb / 8) + blockIdx.x / 8;
  const int bq0 = bswz * QPB;
  const int t = threadIdx.x;

  for (int i = t; i < QPB * 256; i += 256) s_off[i >> 8][i & 255] = off[(size_t)bq0 * 256 + i];
  for (int i = t; i < QPB * 128; i += 256) s_lg[i >> 7][i & 127] = logits[(size_t)bq0 * 128 + i];
  if (t < QPB * 4) s_ref[t >> 2][t & 3] = refpts[(size_t)bq0 * 4 + t];
  __syncthreads();

  const int qi = t >> 5;
  const int sub = t & 31;
  const int h = sub >> 2;
  const int c4 = sub & 3;
  const int bq = bq0 + qi;
  const int b = bq / QQ;

  float w[16];
  {
    const float* lg = &s_lg[qi][h * 16];
    float m = lg[0];
#pragma unroll
    for (int j = 1; j < 16; ++j) m = fmaxf(m, lg[j]);
    float s = 0.f;
#pragma unroll
    for (int j = 0; j < 16; ++j) { w[j] = __expf(lg[j] - m); s += w[j]; }
    float inv = 1.f / s;
#pragma unroll
    for (int j = 0; j < 16; ++j) w[j] *= inv;
  }

  const float rx = s_ref[qi][0], ry = s_ref[qi][1];
  const float rw = s_ref[qi][2], rh = s_ref[qi][3];
  const unsigned short* vb =
      (const unsigned short*)value + (size_t)b * SS * DD + h * DHH + c4 * 8;

  float acc[8];
#pragma unroll
  for (int j = 0; j < 8; ++j) acc[j] = 0.f;

  const int dims[4] = {80, 40, 20, 10};
  const int sts[4] = {0, 6400, 8000, 8400};

#pragma unroll
  for (int l = 0; l < LL; ++l) {
    const int dim = dims[l];
    const int st = sts[l];
    const float fdim = (float)dim;
#pragma unroll
    for (int p = 0; p < PP; ++p) {
      const int tapi = l * 4 + p;
      const int oi = (h * 16 + tapi) * 2;
      const float locx = rx + s_off[qi][oi] * rw * 0.125f;
      const float locy = ry + s_off[qi][oi + 1] * rh * 0.125f;
      const float x = locx * fdim - 0.5f;
      const float y = locy * fdim - 0.5f;
      const float x0f = floorf(x), y0f = floorf(y);
      const float fx = x - x0f, fy = y - y0f;
      const int x0 = (int)x0f, y0 = (int)y0f;
      const float wt = w[tapi];
      const float bw[4] = {(1.f - fx) * (1.f - fy), fx * (1.f - fy),
                           (1.f - fx) * fy, fx * fy};
      const int cx[4] = {x0, x0 + 1, x0, x0 + 1};
      const int cy[4] = {y0, y0, y0 + 1, y0 + 1};
#pragma unroll
      for (int c = 0; c < 4; ++c) {
        const int xi = cx[c], yi = cy[c];
        const bool valid = (xi >= 0) & (xi < dim) & (yi >= 0) & (yi < dim);
        const int xc = min(max(xi, 0), dim - 1);
        const int yc = min(max(yi, 0), dim - 1);
        const uint4 v = *reinterpret_cast<const uint4*>(
            vb + (size_t)(st + yc * dim + xc) * DD);
        const float wv = valid ? bw[c] * wt : 0.f;
        const unsigned u[4] = {v.x, v.y, v.z, v.w};
#pragma unroll
        for (int k = 0; k < 4; ++k) {
          const float lo = __builtin_bit_cast(float, u[k] << 16);
          const float hi = __builtin_bit_cast(float, u[k] & 0xFFFF0000u);
          acc[2 * k] += lo * wv;
          acc[2 * k + 1] += hi * wv;
        }
      }
    }
  }

  float* outp = &sampled[(size_t)bq * 256 + h * DHH + c4 * 8];
  *reinterpret_cast<float4*>(outp) = make_float4(acc[0], acc[1], acc[2], acc[3]);
  *reinterpret_cast<float4*>(outp + 4) = make_float4(acc[4], acc[5], acc[6], acc[7]);
}

// ---------------------------------------------------------------------------
// Launch
// ---------------------------------------------------------------------------
extern "C" void kernel_launch(void* const* d_in, const int* in_sizes, int n_in,
                              void* d_out, int out_size, void* d_ws, size_t ws_size,
                              hipStream_t stream) {
  const float* hidden = (const float*)d_in[0];
  const float* ehs    = (const float*)d_in[1];
  const float* refpts = (const float*)d_in[2];
  const float* W_val  = (const float*)d_in[3];
  const float* b_val  = (const float*)d_in[4];
  const float* W_off  = (const float*)d_in[5];
  const float* b_off  = (const float*)d_in[6];
  const float* W_attn = (const float*)d_in[7];
  const float* b_attn = (const float*)d_in[8];
  const float* W_out  = (const float*)d_in[9];
  const float* b_out  = (const float*)d_in[10];
  float* out = (float*)d_out;

  // Workspace layout
  char* ws = (char*)d_ws;
  __hip_bfloat16* value = (__hip_bfloat16*)ws;                 // 139,264,000 B
  float* offb = (float*)(ws + 139264000);                      // 9,830,400 B
  float* awb  = (float*)(ws + 139264000 + 9830400);            // 4,915,200 B
  float* samp = (float*)(ws + 139264000 + 9830400 + 4915200);  // 9,830,400 B
  unsigned short* wbfS = (unsigned short*)(ws + 139264000 + 9830400 + 4915200 + 9830400);

  const int M_val = BB * SS;   // 272000
  const int M_q   = BB * QQ;   // 9600

  // 0. W_val -> bf16 [n][k], XOR-swizzled
  wcvt_kernel<<<256, 256, 0, stream>>>(W_val, wbfS);
  // 1. value = ehs @ W_val + b_val  (bf16 MFMA, BM=64 full-N, async B stage)
  gemm_val_mfma<<<M_val / 64, 256, 0, stream>>>(ehs, wbfS, b_val, value);
  // 2. off = hidden @ W_off + b_off  (fp32 — feeds sample positions)
  gemm_rowtile<256, float><<<M_q / 32, 256, 0, stream>>>(hidden, W_off, b_off, offb);
  // 3. aw logits = hidden @ W_attn + b_attn (softmax fused into sampling)
  gemm_rowtile<128, float><<<M_q / 32, 256, 0, stream>>>(hidden, W_attn, b_attn, awb);
  // 4. bilinear sampling + fused softmax + weighted sum
  sample_kernel<<<M_q / QPB, 256, 0, stream>>>(value, offb, awb, refpts, samp);
  // 5. out = samp @ W_out + b_out
  gemm_rowtile<256, float><<<M_q / 32, 256, 0, stream>>>(samp, W_out, b_out, out);
}